// Round 10
// baseline (223.662 us; speedup 1.0000x reference)
//
#include <hip/hip_runtime.h>
#include <hip/hip_bf16.h>
#include <cstddef>

#define T_TOK 1024
#define D_DIM 1024
#define H_DIM 512
#define E_EXP 8
#define P_CAP 2560          // max padded pairs: 2048 + 8*31 = 2296 -> 2560
#define MAX_MT 72           // 32-row m-tiles: <= 2296/32 = 71.75 -> 72 slots

typedef __attribute__((ext_vector_type(4))) float    float4_t;
typedef __attribute__((ext_vector_type(8))) short    short8_t;
typedef __attribute__((ext_vector_type(4))) unsigned uint4_t;

__device__ __forceinline__ short f2bf(float f) {
  union { float f; unsigned u; } v; v.f = f;
  unsigned u = v.u;
  u += 0x7FFFu + ((u >> 16) & 1u);
  return (short)(u >> 16);
}

// packed fp32x2 -> bf16x2; low short = a, high = b
__device__ __forceinline__ unsigned pkbf(float a, float b) {
  union { __hip_bfloat162 h; unsigned u; } v;
  v.h = __float22bfloat162_rn(make_float2(a, b));
  return v.u;
}

// ---- prep: weight transpose+convert (z<24) + router (z==24) + out=0 (z==25)
__global__ __launch_bounds__(256) void prep_kernel(
    const float* __restrict__ w1, const float* __restrict__ w3,
    const float* __restrict__ w2, const float* __restrict__ x,
    const float* __restrict__ gw, short* __restrict__ w13t,
    short* __restrict__ w2t, int* __restrict__ idx2,
    float* __restrict__ scale2, float* __restrict__ out) {
  __shared__ float tile[64][69];   // odd stride: transpose reads <=2-way (free)
  const int z = blockIdx.z;
  const int tid = threadIdx.x;

  if (z < 24) {
    const float* src; short* dst; int N, ldd, row_off;
    if (z < 16) {
      if (blockIdx.y >= 8) return;          // N=512 -> 8 n-tiles
      int which = z >> 3, e = z & 7;
      src = (which ? w3 : w1) + (size_t)e * D_DIM * H_DIM;
      dst = w13t + (size_t)e * D_DIM * (2 * H_DIM);
      N = H_DIM; ldd = D_DIM; row_off = which ? H_DIM : 0;
    } else {
      if (blockIdx.x >= 8) return;          // K=512 -> 8 k-tiles
      int e = z - 16;
      src = w2 + (size_t)e * H_DIM * D_DIM;
      dst = w2t + (size_t)e * D_DIM * H_DIM;
      N = D_DIM; ldd = H_DIM; row_off = 0;
    }
    const int k0 = blockIdx.x * 64, n0 = blockIdx.y * 64;
    const int kr = tid >> 4, nc = (tid & 15) * 4;
    #pragma unroll
    for (int p = 0; p < 4; ++p) {
      int k = p * 16 + kr;
      float4_t v = *(const float4_t*)(src + (size_t)(k0 + k) * N + n0 + nc);
      tile[k][nc]     = v[0];
      tile[k][nc + 1] = v[1];
      tile[k][nc + 2] = v[2];
      tile[k][nc + 3] = v[3];
    }
    __syncthreads();
    const int r8 = tid >> 3, c8 = tid & 7;
    #pragma unroll
    for (int p = 0; p < 2; ++p) {
      int row = p * 32 + r8;
      uint4_t u;
      #pragma unroll
      for (int jj = 0; jj < 4; ++jj)
        u[jj] = pkbf(tile[c8 * 8 + 2 * jj][row], tile[c8 * 8 + 2 * jj + 1][row]);
      *(uint4_t*)(dst + (size_t)(row_off + n0 + row) * ldd + k0 + c8 * 8) = u;
    }
    return;
  }

  if (z == 25) {                            // zero out[] : 256 blocks x 16KB
    float4_t z4 = {0.f, 0.f, 0.f, 0.f};
    float4_t* o = (float4_t*)(out + ((size_t)(blockIdx.y * 16 + blockIdx.x)) * 4096);
    #pragma unroll
    for (int i = 0; i < 4; ++i) o[i * 256 + tid] = z4;
    return;
  }

  // z == 24: router, 4 tokens per block (one wave each)
  const int wid  = tid >> 6;
  const int lane = tid & 63;
  const int t = (blockIdx.y * 16 + blockIdx.x) * 4 + wid;
  const float* xr = x + (size_t)t * D_DIM;
  float acc[E_EXP];
  #pragma unroll
  for (int e = 0; e < E_EXP; ++e) acc[e] = 0.f;
  for (int d = lane; d < D_DIM; d += 64) {
    float xv = xr[d];
    float4_t g0 = *(const float4_t*)(gw + d * E_EXP);
    float4_t g1 = *(const float4_t*)(gw + d * E_EXP + 4);
    acc[0] += xv * g0[0]; acc[1] += xv * g0[1];
    acc[2] += xv * g0[2]; acc[3] += xv * g0[3];
    acc[4] += xv * g1[0]; acc[5] += xv * g1[1];
    acc[6] += xv * g1[2]; acc[7] += xv * g1[3];
  }
  #pragma unroll
  for (int off = 32; off >= 1; off >>= 1) {
    #pragma unroll
    for (int e = 0; e < E_EXP; ++e) acc[e] += __shfl_down(acc[e], off, 64);
  }
  if (lane == 0) {
    float m = acc[0];
    #pragma unroll
    for (int e = 1; e < E_EXP; ++e) m = fmaxf(m, acc[e]);
    float p[E_EXP]; float s = 0.f;
    #pragma unroll
    for (int e = 0; e < E_EXP; ++e) { p[e] = __expf(acc[e] - m); s += p[e]; }
    float inv = 1.f / s;
    #pragma unroll
    for (int e = 0; e < E_EXP; ++e) p[e] *= inv;
    int i1 = 0;
    #pragma unroll
    for (int e = 1; e < E_EXP; ++e) if (p[e] > p[i1]) i1 = e;  // jax low-index tiebreak
    int i2 = (i1 == 0) ? 1 : 0;
    #pragma unroll
    for (int e = 0; e < E_EXP; ++e) {
      if (e == i1 || e == i2) continue;
      if (p[e] > p[i2]) i2 = e;
    }
    idx2[2 * t]     = i1;  scale2[2 * t]     = p[i1];
    idx2[2 * t + 1] = i2;  scale2[2 * t + 1] = p[i2];
  }
}

// ---- scan/assign: histogram -> 32-aligned bases -> tile table -> pair lists
__global__ __launch_bounds__(256) void scan_kernel(
    const int* __restrict__ idx2, const float* __restrict__ scale2,
    int* __restrict__ pair_tok, float* __restrict__ pair_scale,
    int* __restrict__ meta) {
  __shared__ int cnt[E_EXP], base[E_EXP], cur[E_EXP];
  const int tid = threadIdx.x;
  if (tid < E_EXP) { cnt[tid] = 0; cur[tid] = 0; }
  for (int p = tid; p < P_CAP; p += 256) { pair_tok[p] = -1; pair_scale[p] = 0.f; }
  __syncthreads();
  for (int t = tid; t < T_TOK; t += 256) {
    atomicAdd(&cnt[idx2[2 * t]], 1);
    atomicAdd(&cnt[idx2[2 * t + 1]], 1);
  }
  __syncthreads();
  if (tid == 0) {
    int b = 0, g = 0;
    for (int e = 0; e < E_EXP; ++e) {
      base[e] = b;
      int al = (cnt[e] + 31) & ~31;       // 32-row tiles
      for (int j = 0; j < al; j += 32) { meta[1 + g] = e; meta[81 + g] = b + j; ++g; }
      b += al;
    }
    meta[0] = g;  // n_mtiles (<= 72)
  }
  __syncthreads();
  for (int t = tid; t < T_TOK; t += 256) {
    #pragma unroll
    for (int s = 0; s < 2; ++s) {
      int e = idx2[2 * t + s];
      int p = base[e] + atomicAdd(&cur[e], 1);
      pair_tok[p] = t;
      pair_scale[p] = scale2[2 * t + s];
    }
  }
}

// ------- gemm1: h[p][H] = silu((s*x)@w1e) * ((s*x)@w3e) ---------------------
// Register-direct MFMA: NO LDS, NO barriers. Each wave gathers its own A/B
// fragments straight from global (A: 16 rows x 64B/row; B: pre-transposed
// [n][k] bf16, 16 rows x 64B/row -> full cache lines). The K-loop is a pure
// load->pack->MFMA dataflow chain the compiler can pipeline (unroll 4); wave
// latency hiding needs no __syncthreads convoy (rounds 2-9's structural floor).
__global__ __launch_bounds__(256, 4) void gemm1_kernel(
    const float* __restrict__ x, const short* __restrict__ w13t,
    const int* __restrict__ pair_tok, const float* __restrict__ pair_scale,
    const int* __restrict__ meta, short* __restrict__ h) {
  const int mt = blockIdx.y;
  if (mt >= meta[0]) return;
  const int e    = meta[1 + mt];
  const int row0 = meta[81 + mt];
  const int n0   = blockIdx.x * 32;
  const int tid = threadIdx.x, lane = tid & 63, wid = tid >> 6;
  const int wr = wid >> 1, wc = wid & 1;        // wave: 16m x 16n (x2 matrices)
  const int q = lane >> 4, ln = lane & 15;

  const int   mrow = row0 + wr * 16 + ln;
  const int   tokr = pair_tok[mrow];
  const float sc   = pair_scale[mrow];          // 0 for pad rows -> zeros
  const float* ap  = x + (size_t)(tokr < 0 ? 0 : tokr) * D_DIM + q * 8;

  const int ncol = n0 + wc * 16 + ln;
  const short* bsrc = w13t + (size_t)e * D_DIM * (2 * H_DIM);
  const short* b1p = bsrc + (size_t)ncol * D_DIM + q * 8;
  const short* b3p = bsrc + (size_t)(H_DIM + ncol) * D_DIM + q * 8;

  float4_t acc1 = {0.f, 0.f, 0.f, 0.f}, acc3 = {0.f, 0.f, 0.f, 0.f};

  #pragma unroll 4
  for (int k0 = 0; k0 < D_DIM; k0 += 32) {
    float4_t v0 = *(const float4_t*)(ap + k0);
    float4_t v1 = *(const float4_t*)(ap + k0 + 4);
    short8_t b1 = *(const short8_t*)(b1p + k0);
    short8_t b3 = *(const short8_t*)(b3p + k0);
    uint4_t ua = {pkbf(v0[0] * sc, v0[1] * sc), pkbf(v0[2] * sc, v0[3] * sc),
                  pkbf(v1[0] * sc, v1[1] * sc), pkbf(v1[2] * sc, v1[3] * sc)};
    short8_t af = *(short8_t*)&ua;
    acc1 = __builtin_amdgcn_mfma_f32_16x16x32_bf16(af, b1, acc1, 0, 0, 0);
    acc3 = __builtin_amdgcn_mfma_f32_16x16x32_bf16(af, b3, acc3, 0, 0, 0);
  }

  // epilogue: C layout col=ln, row=q*4+rr
  const int r_base = row0 + wr * 16 + q * 4;
  const int col = n0 + wc * 16 + ln;
  #pragma unroll
  for (int rr = 0; rr < 4; ++rr) {
    float c1 = acc1[rr];
    float c3 = acc3[rr];
    float sig = 1.f / (1.f + __expf(-c1));
    h[(size_t)(r_base + rr) * H_DIM + col] = f2bf(c1 * sig * c3);
  }
}

// -- gemm2 (fused combine): out[tok] += h[p][H] @ w2t[e] ---------------------
// Register-direct, no LDS/barriers; wave = 16m x 16n, K=512 -> 16 iters.
__global__ __launch_bounds__(256, 8) void gemm2_kernel(
    const short* __restrict__ h, const short* __restrict__ w2t,
    const int* __restrict__ pair_tok, const int* __restrict__ meta,
    float* __restrict__ out) {
  const int mt = blockIdx.y;
  if (mt >= meta[0]) return;
  const int e    = meta[1 + mt];
  const int row0 = meta[81 + mt];
  const int n0   = blockIdx.x * 32;
  const int tid = threadIdx.x, lane = tid & 63, wid = tid >> 6;
  const int wr = wid >> 1, wc = wid & 1;        // wave: 16m x 16n
  const int q = lane >> 4, ln = lane & 15;

  const int mrow = row0 + wr * 16 + ln;
  const short* arow = h + (size_t)mrow * H_DIM + q * 8;
  const int ncol = n0 + wc * 16 + ln;
  const short* bp = w2t + (size_t)e * D_DIM * H_DIM + (size_t)ncol * H_DIM + q * 8;

  float4_t acc = {0.f, 0.f, 0.f, 0.f};

  #pragma unroll 4
  for (int k0 = 0; k0 < H_DIM; k0 += 32) {
    short8_t af = *(const short8_t*)(arow + k0);
    short8_t bf = *(const short8_t*)(bp + k0);
    acc = __builtin_amdgcn_mfma_f32_16x16x32_bf16(af, bf, acc, 0, 0, 0);
  }

  // epilogue: scatter-add into out[tok]; skip pad rows (tok < 0)
  const int r_base = row0 + wr * 16 + q * 4;
  const int col = n0 + wc * 16 + ln;
  #pragma unroll
  for (int rr = 0; rr < 4; ++rr) {
    int tok = pair_tok[r_base + rr];
    if (tok < 0) continue;
    atomicAdd(out + (size_t)tok * D_DIM + col, acc[rr]);
  }
}

extern "C" void kernel_launch(void* const* d_in, const int* in_sizes, int n_in,
                              void* d_out, int out_size, void* d_ws, size_t ws_size,
                              hipStream_t stream) {
  const float* x  = (const float*)d_in[0];   // [2,512,1024]
  const float* gw = (const float*)d_in[1];   // [1024,8]
  const float* w1 = (const float*)d_in[2];   // [8,1024,512] gate
  const float* w2 = (const float*)d_in[3];   // [8,512,1024] down
  const float* w3 = (const float*)d_in[4];   // [8,1024,512] up
  float* out = (float*)d_out;

  char* ws = (char*)d_ws;
  int*   idx2    = (int*)  (ws);                       // 8KB
  float* scale2  = (float*)(ws + 8192);                // 8KB
  int*   ptok    = (int*)  (ws + 16384);               // 10KB (16KB slot)
  float* pscale  = (float*)(ws + 32768);               // 10KB (16KB slot)
  int*   meta    = (int*)  (ws + 49152);               // 640B (16KB slot)
  short* h       = (short*)(ws + (1u << 20));          // 2.62 MB
  short* w13t    = (short*)(ws + (4u << 20));          // 16.8 MB
  short* w2t     = (short*)(ws + (21u << 20));         // 8.4 MB

  prep_kernel<<<dim3(16, 16, 26), dim3(256), 0, stream>>>(
      w1, w3, w2, x, gw, w13t, w2t, idx2, scale2, out);
  scan_kernel<<<dim3(1), dim3(256), 0, stream>>>(idx2, scale2, ptok, pscale, meta);
  gemm1_kernel<<<dim3(H_DIM / 32, MAX_MT), dim3(256), 0, stream>>>(
      x, w13t, ptok, pscale, meta, h);
  gemm2_kernel<<<dim3(D_DIM / 32, MAX_MT), dim3(256), 0, stream>>>(
      h, w2t, ptok, meta, out);
}

// Round 11
// 153.097 us; speedup vs baseline: 1.4609x; 1.4609x over previous
//
#include <hip/hip_runtime.h>
#include <hip/hip_bf16.h>
#include <cstddef>

#define T_TOK 1024
#define D_DIM 1024
#define H_DIM 512
#define E_EXP 8
#define P_CAP 2560          // max padded pairs: 2048 + 8*31 = 2296 -> 2560
#define MAX_MT 72           // 32-row m-tiles: <= 2296/32 = 71.75 -> 72 slots
#define LDA 72              // shorts per LDS row: 64 data + 8 pad (144B, 16B-aligned)
#define LDAW 36             // LDA in 4B words

typedef __attribute__((ext_vector_type(4))) float    float4_t;
typedef __attribute__((ext_vector_type(8))) short    short8_t;
typedef __attribute__((ext_vector_type(4))) unsigned uint4_t;
typedef __attribute__((ext_vector_type(2))) unsigned uint2_t;

__device__ __forceinline__ short f2bf(float f) {
  union { float f; unsigned u; } v; v.f = f;
  unsigned u = v.u;
  u += 0x7FFFu + ((u >> 16) & 1u);
  return (short)(u >> 16);
}

// packed fp32x2 -> bf16x2; low short = a, high = b
__device__ __forceinline__ unsigned pkbf(float a, float b) {
  union { __hip_bfloat162 h; unsigned u; } v;
  v.h = __float22bfloat162_rn(make_float2(a, b));
  return v.u;
}

// ---- prep: out-zero (bid<256) + router (bid>=256). No weight conversion:
// the GEMMs stage B straight from fp32 (saves the 50MB write + 50MB re-read).
__global__ __launch_bounds__(256) void prep_kernel(
    const float* __restrict__ x, const float* __restrict__ gw,
    int* __restrict__ idx2, float* __restrict__ scale2,
    float* __restrict__ out) {
  const int bid = blockIdx.x;
  const int tid = threadIdx.x;

  if (bid < 256) {                          // zero out[]: 256 x 16KB chunks
    float4_t z4 = {0.f, 0.f, 0.f, 0.f};
    float4_t* o = (float4_t*)(out + (size_t)bid * 4096);
    #pragma unroll
    for (int i = 0; i < 4; ++i) o[i * 256 + tid] = z4;
    return;
  }

  // router: 4 tokens per block (one wave each)
  const int wid  = tid >> 6;
  const int lane = tid & 63;
  const int t = (bid - 256) * 4 + wid;
  const float* xr = x + (size_t)t * D_DIM;
  float acc[E_EXP];
  #pragma unroll
  for (int e = 0; e < E_EXP; ++e) acc[e] = 0.f;
  for (int d = lane; d < D_DIM; d += 64) {
    float xv = xr[d];
    float4_t g0 = *(const float4_t*)(gw + d * E_EXP);
    float4_t g1 = *(const float4_t*)(gw + d * E_EXP + 4);
    acc[0] += xv * g0[0]; acc[1] += xv * g0[1];
    acc[2] += xv * g0[2]; acc[3] += xv * g0[3];
    acc[4] += xv * g1[0]; acc[5] += xv * g1[1];
    acc[6] += xv * g1[2]; acc[7] += xv * g1[3];
  }
  #pragma unroll
  for (int off = 32; off >= 1; off >>= 1) {
    #pragma unroll
    for (int e = 0; e < E_EXP; ++e) acc[e] += __shfl_down(acc[e], off, 64);
  }
  if (lane == 0) {
    float m = acc[0];
    #pragma unroll
    for (int e = 1; e < E_EXP; ++e) m = fmaxf(m, acc[e]);
    float p[E_EXP]; float s = 0.f;
    #pragma unroll
    for (int e = 0; e < E_EXP; ++e) { p[e] = __expf(acc[e] - m); s += p[e]; }
    float inv = 1.f / s;
    #pragma unroll
    for (int e = 0; e < E_EXP; ++e) p[e] *= inv;
    int i1 = 0;
    #pragma unroll
    for (int e = 1; e < E_EXP; ++e) if (p[e] > p[i1]) i1 = e;  // jax low-index tiebreak
    int i2 = (i1 == 0) ? 1 : 0;
    #pragma unroll
    for (int e = 0; e < E_EXP; ++e) {
      if (e == i1 || e == i2) continue;
      if (p[e] > p[i2]) i2 = e;
    }
    idx2[2 * t]     = i1;  scale2[2 * t]     = p[i1];
    idx2[2 * t + 1] = i2;  scale2[2 * t + 1] = p[i2];
  }
}

// ---- scan/assign: histogram -> 32-aligned bases -> tile table -> pair lists
__global__ __launch_bounds__(256) void scan_kernel(
    const int* __restrict__ idx2, const float* __restrict__ scale2,
    int* __restrict__ pair_tok, float* __restrict__ pair_scale,
    int* __restrict__ meta) {
  __shared__ int cnt[E_EXP], base[E_EXP], cur[E_EXP];
  const int tid = threadIdx.x;
  if (tid < E_EXP) { cnt[tid] = 0; cur[tid] = 0; }
  for (int p = tid; p < P_CAP; p += 256) { pair_tok[p] = -1; pair_scale[p] = 0.f; }
  __syncthreads();
  for (int t = tid; t < T_TOK; t += 256) {
    atomicAdd(&cnt[idx2[2 * t]], 1);
    atomicAdd(&cnt[idx2[2 * t + 1]], 1);
  }
  __syncthreads();
  if (tid == 0) {
    int b = 0, g = 0;
    for (int e = 0; e < E_EXP; ++e) {
      base[e] = b;
      int al = (cnt[e] + 31) & ~31;       // 32-row tiles
      for (int j = 0; j < al; j += 32) { meta[1 + g] = e; meta[81 + g] = b + j; ++g; }
      b += al;
    }
    meta[0] = g;  // n_mtiles (<= 72)
  }
  __syncthreads();
  for (int t = tid; t < T_TOK; t += 256) {
    #pragma unroll
    for (int s = 0; s < 2; ++s) {
      int e = idx2[2 * t + s];
      int p = base[e] + atomicAdd(&cur[e], 1);
      pair_tok[p] = t;
      pair_scale[p] = scale2[2 * t + s];
    }
  }
}

// ------- gemm1: h[p][H] = silu((s*x)@w1e) * ((s*x)@w3e); 32m x 32n ---------
// B staged inline from fp32 w1/w3 (transpose+convert during staging).
__global__ __launch_bounds__(256, 6) void gemm1_kernel(
    const float* __restrict__ x, const float* __restrict__ w1,
    const float* __restrict__ w3,
    const int* __restrict__ pair_tok, const float* __restrict__ pair_scale,
    const int* __restrict__ meta, short* __restrict__ h) {
  __shared__ short As[32 * LDA];    // 4.6 KB
  __shared__ short B1s[32 * LDA];   // 4.6 KB
  __shared__ short B3s[32 * LDA];   // 4.6 KB
  const int mt = blockIdx.y;
  if (mt >= meta[0]) return;
  const int e    = meta[1 + mt];
  const int row0 = meta[81 + mt];
  const int n0   = blockIdx.x * 32;
  const int tid = threadIdx.x, lane = tid & 63, wid = tid >> 6;
  const int wr = wid >> 1, wc = wid & 1;        // 2x2 waves, each 16m x 16n
  const int q = lane >> 4, ln = lane & 15;
  const float* w1e = w1 + (size_t)e * D_DIM * H_DIM;
  const float* w3e = w3 + (size_t)e * D_DIM * H_DIM;

  // A staging: thread owns one 8-float k-segment of one row (gather + scale)
  const int ar = tid >> 3, ak = (tid & 7) * 8;
  const int   tokr = pair_tok[row0 + ar];
  const float sc   = pair_scale[row0 + ar];     // 0 for pad rows -> zeros
  const float* xrow = x + (size_t)(tokr < 0 ? 0 : tokr) * D_DIM + ak;
  // B staging: thread owns a k-pair (2 rows) x 4 n; n fastest in tid for
  // coalescing (8 lanes x 16B = 128B per k-row).
  const int kd = tid >> 3;            // 0..31 k-pair
  const int n4 = (tid & 7) * 4;       // 0..28 n
  const float* b1p = w1e + (size_t)(2 * kd) * H_DIM + n0 + n4;
  const float* b3p = w3e + (size_t)(2 * kd) * H_DIM + n0 + n4;
  unsigned* B1w = (unsigned*)B1s;
  unsigned* B3w = (unsigned*)B3s;

  float4_t acc1 = {0.f, 0.f, 0.f, 0.f}, acc3 = {0.f, 0.f, 0.f, 0.f};

  for (int k0 = 0; k0 < D_DIM; k0 += 64) {
    float4_t v0 = *(const float4_t*)(xrow + k0);
    float4_t v1 = *(const float4_t*)(xrow + k0 + 4);
    const float* bk1 = b1p + (size_t)k0 * H_DIM;
    const float* bk3 = b3p + (size_t)k0 * H_DIM;
    float4_t a0 = *(const float4_t*)(bk1);
    float4_t a1 = *(const float4_t*)(bk1 + H_DIM);
    float4_t c0 = *(const float4_t*)(bk3);
    float4_t c1 = *(const float4_t*)(bk3 + H_DIM);
    uint4_t u0 = {pkbf(v0[0] * sc, v0[1] * sc), pkbf(v0[2] * sc, v0[3] * sc),
                  pkbf(v1[0] * sc, v1[1] * sc), pkbf(v1[2] * sc, v1[3] * sc)};
    *(uint4_t*)&As[ar * LDA + ak] = u0;
    #pragma unroll
    for (int i = 0; i < 4; ++i) {
      B1w[(n4 + i) * LDAW + kd] = pkbf(a0[i], a1[i]);   // bf16x2 = k,k+1
      B3w[(n4 + i) * LDAW + kd] = pkbf(c0[i], c1[i]);
    }
    __syncthreads();

    short8_t af[2], b1f[2], b3f[2];
    #pragma unroll
    for (int kk = 0; kk < 2; ++kk) {
      af[kk]  = *(const short8_t*)&As[(wr * 16 + ln) * LDA + kk * 32 + q * 8];
      b1f[kk] = *(const short8_t*)&B1s[(wc * 16 + ln) * LDA + kk * 32 + q * 8];
      b3f[kk] = *(const short8_t*)&B3s[(wc * 16 + ln) * LDA + kk * 32 + q * 8];
    }
    #pragma unroll
    for (int kk = 0; kk < 2; ++kk) {
      acc1 = __builtin_amdgcn_mfma_f32_16x16x32_bf16(af[kk], b1f[kk], acc1, 0, 0, 0);
      acc3 = __builtin_amdgcn_mfma_f32_16x16x32_bf16(af[kk], b3f[kk], acc3, 0, 0, 0);
    }
    __syncthreads();
  }

  {
    int r_base = row0 + wr * 16 + q * 4;
    int col = n0 + wc * 16 + ln;
    #pragma unroll
    for (int rr = 0; rr < 4; ++rr) {
      float c1 = acc1[rr];
      float c3 = acc3[rr];
      float sig = 1.f / (1.f + __expf(-c1));
      h[(size_t)(r_base + rr) * H_DIM + col] = f2bf(c1 * sig * c3);
    }
  }
}

// -- gemm2 (fused combine): out[tok] += h[p][H] @ w2e; 32m x 64n -------------
// B staged inline from fp32 w2 (transpose+convert during staging).
__global__ __launch_bounds__(256, 6) void gemm2_kernel(
    const short* __restrict__ h, const float* __restrict__ w2,
    const int* __restrict__ pair_tok, const int* __restrict__ meta,
    float* __restrict__ out) {
  __shared__ short As[32 * LDA];   // 4.6 KB
  __shared__ short Bs[64 * LDA];   // 9.2 KB
  const int mt = blockIdx.y;
  if (mt >= meta[0]) return;
  const int e    = meta[1 + mt];
  const int row0 = meta[81 + mt];
  const int n0   = blockIdx.x * 64;
  const int tid = threadIdx.x, lane = tid & 63, wid = tid >> 6;
  const int wr = wid >> 1, wc = wid & 1;        // 2x2 waves, each 16m x 32n
  const int q = lane >> 4, ln = lane & 15;
  const float* w2e = w2 + (size_t)e * H_DIM * D_DIM;   // [512 k][1024 n]

  const int ar = tid >> 3, ak = (tid & 7) * 8;
  const short* arow = h + (size_t)(row0 + ar) * H_DIM + ak;
  // B staging: thread owns a k-quad (4 rows) x 4 n; n fastest for coalescing
  // (16 lanes x 16B = 256B per k-row).
  const int kq = tid >> 4;            // 0..15 k-quad
  const int n4 = (tid & 15) * 4;      // 0..60 n
  const float* bp = w2e + (size_t)(4 * kq) * D_DIM + n0 + n4;
  unsigned* Bw = (unsigned*)Bs;

  float4_t acc[2];
  acc[0] = acc[1] = (float4_t){0.f, 0.f, 0.f, 0.f};

  for (int k0 = 0; k0 < H_DIM; k0 += 64) {
    uint4_t va = *(const uint4_t*)(arow + k0);
    const float* bk = bp + (size_t)k0 * D_DIM;
    float4_t r0 = *(const float4_t*)(bk);
    float4_t r1 = *(const float4_t*)(bk + D_DIM);
    float4_t r2 = *(const float4_t*)(bk + 2 * D_DIM);
    float4_t r3 = *(const float4_t*)(bk + 3 * D_DIM);
    *(uint4_t*)&As[ar * LDA + ak] = va;
    #pragma unroll
    for (int i = 0; i < 4; ++i) {
      uint2_t u = {pkbf(r0[i], r1[i]), pkbf(r2[i], r3[i])};  // k..k+3
      *(uint2_t*)&Bw[(n4 + i) * LDAW + kq * 2] = u;
    }
    __syncthreads();

    short8_t af[2], bf[2][2];
    #pragma unroll
    for (int kk = 0; kk < 2; ++kk) {
      af[kk] = *(const short8_t*)&As[(wr * 16 + ln) * LDA + kk * 32 + q * 8];
      #pragma unroll
      for (int j = 0; j < 2; ++j)
        bf[j][kk] = *(const short8_t*)&Bs[(wc * 32 + j * 16 + ln) * LDA + kk * 32 + q * 8];
    }
    #pragma unroll
    for (int j = 0; j < 2; ++j)
      #pragma unroll
      for (int kk = 0; kk < 2; ++kk)
        acc[j] = __builtin_amdgcn_mfma_f32_16x16x32_bf16(af[kk], bf[j][kk], acc[j], 0, 0, 0);
    __syncthreads();
  }

  // ---- epilogue: scatter-add into out[tok]; skip pad rows (tok < 0)
  {
    int r_base = row0 + wr * 16 + q * 4;
    #pragma unroll
    for (int rr = 0; rr < 4; ++rr) {
      int tok = pair_tok[r_base + rr];
      if (tok < 0) continue;
      float* orow = out + (size_t)tok * D_DIM;
      #pragma unroll
      for (int j = 0; j < 2; ++j) {
        int col = n0 + wc * 32 + j * 16 + ln;
        atomicAdd(orow + col, acc[j][rr]);
      }
    }
  }
}

extern "C" void kernel_launch(void* const* d_in, const int* in_sizes, int n_in,
                              void* d_out, int out_size, void* d_ws, size_t ws_size,
                              hipStream_t stream) {
  const float* x  = (const float*)d_in[0];   // [2,512,1024]
  const float* gw = (const float*)d_in[1];   // [1024,8]
  const float* w1 = (const float*)d_in[2];   // [8,1024,512] gate
  const float* w2 = (const float*)d_in[3];   // [8,512,1024] down
  const float* w3 = (const float*)d_in[4];   // [8,1024,512] up
  float* out = (float*)d_out;

  char* ws = (char*)d_ws;
  int*   idx2    = (int*)  (ws);                       // 8KB
  float* scale2  = (float*)(ws + 8192);                // 8KB
  int*   ptok    = (int*)  (ws + 16384);               // 10KB (16KB slot)
  float* pscale  = (float*)(ws + 32768);               // 10KB (16KB slot)
  int*   meta    = (int*)  (ws + 49152);               // 640B (16KB slot)
  short* h       = (short*)(ws + (1u << 20));          // 2.62 MB

  prep_kernel<<<dim3(512), dim3(256), 0, stream>>>(x, gw, idx2, scale2, out);
  scan_kernel<<<dim3(1), dim3(256), 0, stream>>>(idx2, scale2, ptok, pscale, meta);
  gemm1_kernel<<<dim3(H_DIM / 32, MAX_MT), dim3(256), 0, stream>>>(
      x, w1, w3, ptok, pscale, meta, h);
  gemm2_kernel<<<dim3(D_DIM / 64, MAX_MT), dim3(256), 0, stream>>>(
      h, w2, ptok, meta, out);
}